// Round 1
// baseline (55.415 us; speedup 1.0000x reference)
//
#include <hip/hip_runtime.h>
#include <math.h>

#define NB_B 8
#define NB_C 256
#define NB_HW 9216          // 96*96
#define TOTPIX 73728        // 8*9216
#define NBLK 1024           // 32*32 blocks per batch
#define NFLAT 9216          // flat elems per batch (region)
// lower median of 9216 elems = sorted flat idx 4607 = block rank 4607/9 = 511

// ---------------- kernel 1: partial channel reduction ----------------
// part[chunk][pix] = sum over 64 channels of (rec-align)^2
template<int NCH>
__global__ __launch_bounds__(256) void k_loss_partial(const float* __restrict__ rec,
                                                      const float* __restrict__ al,
                                                      float* __restrict__ part) {
  const int pix = blockIdx.x * 256 + threadIdx.x;      // 0..73727
  const int chunk = blockIdx.y;                         // 0..NCH-1
  const int cpc = NB_C / NCH;
  const int b = pix / NB_HW;
  const int p = pix - b * NB_HW;
  const size_t base = (size_t)b * NB_C * NB_HW + (size_t)chunk * cpc * NB_HW + p;
  const float* pr = rec + base;
  const float* pa = al + base;
  float a0 = 0.f, a1 = 0.f, a2 = 0.f, a3 = 0.f;
  for (int c = 0; c < cpc; c += 4) {
    float d0 = pr[(size_t)(c + 0) * NB_HW] - pa[(size_t)(c + 0) * NB_HW];
    float d1 = pr[(size_t)(c + 1) * NB_HW] - pa[(size_t)(c + 1) * NB_HW];
    float d2 = pr[(size_t)(c + 2) * NB_HW] - pa[(size_t)(c + 2) * NB_HW];
    float d3 = pr[(size_t)(c + 3) * NB_HW] - pa[(size_t)(c + 3) * NB_HW];
    a0 = fmaf(d0, d0, a0);
    a1 = fmaf(d1, d1, a1);
    a2 = fmaf(d2, d2, a2);
    a3 = fmaf(d3, d3, a3);
  }
  part[(size_t)chunk * TOTPIX + pix] = (a0 + a1) + (a2 + a3);
}

// ---------------- kernel 2: fold chunks + 3x3 block means ----------------
__global__ __launch_bounds__(256) void k_blocks(const float* __restrict__ part,
                                                float* __restrict__ blocks, int nch) {
  int id = blockIdx.x * 256 + threadIdx.x;             // 0..8191
  if (id >= NB_B * NBLK) return;
  int b = id >> 10;
  int r = id & 1023;
  int bi = r >> 5, bj = r & 31;
  int base_p = (bi * 3) * 96 + bj * 3;
  float s = 0.f;
  for (int ch = 0; ch < nch; ++ch) {
    const float* lp = part + (size_t)ch * TOTPIX + (size_t)b * NB_HW + base_p;
#pragma unroll
    for (int dy = 0; dy < 3; ++dy)
#pragma unroll
      for (int dx = 0; dx < 3; ++dx)
        s += lp[dy * 96 + dx];
  }
  blocks[id] = s * (1.0f / (256.0f * 9.0f));           // mean over C then over 3x3
}

// ---------------- kernel 3: per-batch sort + stats + weighted sum ----------------
__global__ __launch_bounds__(256) void k_stats(const float* __restrict__ blocks,
                                               double* __restrict__ bsums) {
  __shared__ float s[NBLK];
  __shared__ double red[256];
  const int b = blockIdx.x;
  const int t = threadIdx.x;
  for (int i = t; i < NBLK; i += 256) s[i] = blocks[b * NBLK + i];
  __syncthreads();

  // bitonic sort ascending (1024 elems, 256 threads, 4 pairs/thread per step)
  for (int k = 2; k <= NBLK; k <<= 1) {
    for (int j = k >> 1; j > 0; j >>= 1) {
      for (int base = 0; base < NBLK; base += 256) {
        int idx = base + t;
        int ixj = idx ^ j;
        if (ixj > idx) {
          float a = s[idx], c2 = s[ixj];
          bool up = ((idx & k) == 0);
          if ((a > c2) == up) { s[idx] = c2; s[ixj] = a; }
        }
      }
      __syncthreads();
    }
  }

  // mean
  double lp = 0.0;
  for (int i = t; i < NBLK; i += 256) lp += (double)s[i];
  red[t] = lp; __syncthreads();
  for (int w = 128; w > 0; w >>= 1) { if (t < w) red[t] += red[t + w]; __syncthreads(); }
  double mean = red[0] / 1024.0;
  __syncthreads();

  // sum of squared deviations over blocks; flat variance = 9*SS/9215 (ddof=1)
  double ss = 0.0;
  for (int i = t; i < NBLK; i += 256) { double d = (double)s[i] - mean; ss += d * d; }
  red[t] = ss; __syncthreads();
  for (int w = 128; w > 0; w >>= 1) { if (t < w) red[t] += red[t + w]; __syncthreads(); }
  double var = 9.0 * red[0] / 9215.0;
  float stdv = (float)sqrt(var);
  float safe = fmaxf(stdv, 1e-3f);
  float med = s[511];                                  // lower median of the 9x-repeated flat
  __syncthreads();

  // weighted sum: each block contributes 9 * v * (1 + 2*sigmoid((v-med)/safe))
  double wsum = 0.0;
  for (int i = t; i < NBLK; i += 256) {
    float v = s[i];
    float z = (v - med) / safe;
    float sig = 1.0f / (1.0f + expf(-z));
    wsum += (double)(9.0f * v) * (double)(1.0f + 2.0f * sig);
  }
  red[t] = wsum; __syncthreads();
  for (int w = 128; w > 0; w >>= 1) { if (t < w) red[t] += red[t + w]; __syncthreads(); }
  if (t == 0) bsums[b] = red[0];
}

// ---------------- kernel 4: combine batches ----------------
__global__ void k_final(const double* __restrict__ bsums, float* __restrict__ out) {
  if (threadIdx.x == 0 && blockIdx.x == 0) {
    double st = 0.0;
    for (int b = 0; b < NB_B; ++b) st += bsums[b];
    out[0] = (float)(st / (double)TOTPIX);
  }
}

extern "C" void kernel_launch(void* const* d_in, const int* in_sizes, int n_in,
                              void* d_out, int out_size, void* d_ws, size_t ws_size,
                              hipStream_t stream) {
  const float* rec = (const float*)d_in[0];
  const float* al  = (const float*)d_in[1];
  float* out = (float*)d_out;
  char* ws = (char*)d_ws;

  // ws layout: part[nch][73728] f32 | blocks[8192] f32 | bsums[8] f64
  const size_t need4 = (size_t)4 * TOTPIX * 4 + (size_t)NB_B * NBLK * 4 + 64;
  const int nch = (ws_size >= need4) ? 4 : 1;

  float*  part   = (float*)ws;
  float*  blocks = (float*)(ws + (size_t)nch * TOTPIX * 4);
  double* bsums  = (double*)(ws + (size_t)nch * TOTPIX * 4 + (size_t)NB_B * NBLK * 4);

  if (nch == 4)
    k_loss_partial<4><<<dim3(TOTPIX / 256, 4), 256, 0, stream>>>(rec, al, part);
  else
    k_loss_partial<1><<<dim3(TOTPIX / 256, 1), 256, 0, stream>>>(rec, al, part);

  k_blocks<<<(NB_B * NBLK + 255) / 256, 256, 0, stream>>>(part, blocks, nch);
  k_stats<<<NB_B, 256, 0, stream>>>(blocks, bsums);
  k_final<<<1, 64, 0, stream>>>(bsums, out);
}